// Round 1
// baseline (280.820 us; speedup 1.0000x reference)
//
#include <hip/hip_runtime.h>
#include <math.h>

#define NB 16
#define NH 512
#define NW 512
#define PLANE (NH * NW)
#define INF_D 1.0e9f
#define BIG 3.0e38f
#define TW 32

// ---------------------------------------------------------------------------
// K1: exact 1-D nearest-zero distance along axis 0 (B), squared.
// One thread per (h,w) column; replicates the reference's fwd/bwd min scans
// bit-exactly (INF=1e9, c=min(c+1,d)).
// ---------------------------------------------------------------------------
__global__ __launch_bounds__(256) void k_pass_b(const float* __restrict__ x,
                                                float* __restrict__ d2) {
    int idx = blockIdx.x * 256 + threadIdx.x;  // h*NW + w
    if (idx >= PLANE) return;
    float d0[NB], d[NB];
#pragma unroll
    for (int b = 0; b < NB; ++b) {
        float v = x[(size_t)b * PLANE + idx];
        d0[b] = (v == 0.0f) ? 0.0f : INF_D;  // NaN != 0 -> foreground
    }
    float c = INF_D;
#pragma unroll
    for (int b = 0; b < NB; ++b) {
        c = fminf(c + 1.0f, d0[b]);
        d[b] = c;
    }
    c = INF_D;
#pragma unroll
    for (int b = NB - 1; b >= 0; --b) {
        c = fminf(c + 1.0f, d0[b]);
        d[b] = fminf(d[b], c);
    }
#pragma unroll
    for (int b = 0; b < NB; ++b) {
        d2[(size_t)b * PLANE + idx] = d[b] * d[b];
    }
}

// ---------------------------------------------------------------------------
// K2: exact min-plus parabola along axis 1 (H).
// Block = 512 threads handles one b and a 32-wide w tile, all 512 i.
// LDS tile gs[512][32] = 64 KB. Thread (w = t&31, iq = t>>5) owns
// i = iq*32 .. iq*32+31 (32 accumulators).
// Candidate value fmaf(i-k, i-k, g) is bit-identical to the reference's
// (i-k)**2 + g (exact square, one rounding on the add).
// ---------------------------------------------------------------------------
__global__ __launch_bounds__(512) void k_pass_h(const float* __restrict__ g,
                                                float* __restrict__ out) {
    __shared__ float gs[NH][TW];
    int b = blockIdx.y;
    int w0 = blockIdx.x * TW;
    const float* gb = g + (size_t)b * PLANE + w0;
    int t = threadIdx.x;
    for (int r = t; r < NH * TW; r += 512) {
        int k = r >> 5;
        int w = r & 31;
        gs[k][w] = gb[k * NW + w];
    }
    __syncthreads();

    int w = t & 31;
    int i0 = (t >> 5) * 32;
    float m[32], ifl[32];
#pragma unroll
    for (int j = 0; j < 32; ++j) {
        m[j] = BIG;
        ifl[j] = (float)(i0 + j);
    }
    for (int k = 0; k < NH; ++k) {
        float a = gs[k][w];
        float kf = (float)k;
#pragma unroll
        for (int j = 0; j < 32; ++j) {
            float d = ifl[j] - kf;
            m[j] = fminf(m[j], fmaf(d, d, a));
        }
    }
    float* ob = out + (size_t)b * PLANE + w0;
#pragma unroll
    for (int j = 0; j < 32; ++j) {
        ob[(size_t)(i0 + j) * NW + w] = m[j];
    }
}

// ---------------------------------------------------------------------------
// K3: exact min-plus parabola along axis 2 (W) + sqrt + NaN mask.
// One block (256 threads) per contiguous line (b,h,:); line staged in LDS.
// Each thread owns i = t and t+256.
// ---------------------------------------------------------------------------
__global__ __launch_bounds__(256) void k_pass_w(const float* __restrict__ g,
                                                const float* __restrict__ x,
                                                float* __restrict__ out) {
    __shared__ float gs[NW];
    int b = blockIdx.y;
    int h = blockIdx.x;
    const size_t base = ((size_t)b * NH + h) * NW;
    int t = threadIdx.x;
    gs[t] = g[base + t];
    gs[t + 256] = g[base + t + 256];
    __syncthreads();

    float i1 = (float)t;
    float i2 = (float)(t + 256);
    float m1 = BIG, m2 = BIG;
    float kf = 0.0f;
    for (int k = 0; k < NW; k += 4) {
        float4 a4 = *reinterpret_cast<float4*>(&gs[k]);
#pragma unroll
        for (int u = 0; u < 4; ++u) {
            float a = (&a4.x)[u];
            float kk = kf + (float)u;  // exact: k+u <= 511
            float t1 = i1 - kk;
            float t2 = i2 - kk;
            m1 = fminf(m1, fmaf(t1, t1, a));
            m2 = fminf(m2, fmaf(t2, t2, a));
        }
        kf += 4.0f;
    }
    float v1 = sqrtf(m1);
    float v2 = sqrtf(m2);
    float x1 = x[base + t];
    float x2 = x[base + t + 256];
    out[base + t] = isnan(x1) ? __builtin_nanf("") : v1;
    out[base + t + 256] = isnan(x2) ? __builtin_nanf("") : v2;
}

extern "C" void kernel_launch(void* const* d_in, const int* in_sizes, int n_in,
                              void* d_out, int out_size, void* d_ws, size_t ws_size,
                              hipStream_t stream) {
    (void)in_sizes; (void)n_in; (void)out_size; (void)ws_size;
    const float* x = (const float*)d_in[0];
    float* out = (float*)d_out;
    float* ws = (float*)d_ws;  // needs NB*PLANE*4 = 16.8 MB

    // K1: x -> out holds d^2 after the B-axis pass
    k_pass_b<<<dim3((PLANE + 255) / 256), 256, 0, stream>>>(x, out);
    // K2: min-plus along H: out -> ws
    k_pass_h<<<dim3(NW / TW, NB), 512, 0, stream>>>(out, ws);
    // K3: min-plus along W + sqrt + NaN mask: ws -> out
    k_pass_w<<<dim3(NH, NB), 256, 0, stream>>>(ws, x, out);
}

// Round 3
// 64.442 us; speedup vs baseline: 4.3577x; 4.3577x over previous
//
#include <hip/hip_runtime.h>
#include <math.h>

#define NB 16
#define NH 512
#define NW 512
#define PLANE (NH * NW)
#define INF_D 1.0e9f
#define BIG 3.0e38f

// ---------------------------------------------------------------------------
// K1: exact 1-D nearest-zero distance along axis 0 (B), squared. float4.
// Replicates the reference's fwd/bwd min scans bit-exactly.
// ---------------------------------------------------------------------------
__global__ __launch_bounds__(256) void k_pass_b(const float* __restrict__ x,
                                                float* __restrict__ d2) {
    int idx4 = (blockIdx.x * 256 + threadIdx.x) * 4;  // 4 consecutive (h,w)
    if (idx4 >= PLANE) return;
    float4 d0[NB], d[NB];
#pragma unroll
    for (int b = 0; b < NB; ++b) {
        float4 v = *reinterpret_cast<const float4*>(&x[(size_t)b * PLANE + idx4]);
        d0[b].x = (v.x == 0.0f) ? 0.0f : INF_D;
        d0[b].y = (v.y == 0.0f) ? 0.0f : INF_D;
        d0[b].z = (v.z == 0.0f) ? 0.0f : INF_D;
        d0[b].w = (v.w == 0.0f) ? 0.0f : INF_D;
    }
#pragma unroll
    for (int c = 0; c < 4; ++c) {
        float cc = INF_D;
#pragma unroll
        for (int b = 0; b < NB; ++b) {
            float* p0 = (float*)&d0[b];
            float* p = (float*)&d[b];
            cc = fminf(cc + 1.0f, p0[c]);
            p[c] = cc;
        }
        cc = INF_D;
#pragma unroll
        for (int b = NB - 1; b >= 0; --b) {
            float* p0 = (float*)&d0[b];
            float* p = (float*)&d[b];
            cc = fminf(cc + 1.0f, p0[c]);
            p[c] = fminf(p[c], cc);
        }
    }
#pragma unroll
    for (int b = 0; b < NB; ++b) {
        float4 o;
        o.x = d[b].x * d[b].x;
        o.y = d[b].y * d[b].y;
        o.z = d[b].z * d[b].z;
        o.w = d[b].w * d[b].w;
        *reinterpret_cast<float4*>(&d2[(size_t)b * PLANE + idx4]) = o;
    }
}

// ---------------------------------------------------------------------------
// K2: exact min-plus parabola along axis 1 (H) with segment-ring pruning.
// Block = 256 threads: one b, 16-wide w tile, all 512 i.
// Thread (w = t&15, q = t>>4) owns outputs i = 32q..32q+31.
// h[k] = g[k] + k^2 staged in LDS; candidate = fma(-2i, k, h[k]); result
// = i^2 + min. All finite-path values are integers < 2^24 -> bit-exact.
// Pruning in TRUE space: bmax = max_j (i_j^2 + best[j]). Segment s (32 k's)
// at ring r skippable when gap^2 + min_seg(g) >= bmax, gap = 32r-31; all
// rings >= r skippable when gap^2 >= bmax (g >= 0).
// ---------------------------------------------------------------------------
#define TW2 16
__global__ __launch_bounds__(256) void k_pass_h(const float* __restrict__ g,
                                                float* __restrict__ out) {
    __shared__ float hs[NH * TW2];     // [k][w]  32 KB
    __shared__ float smin[16 * TW2];   // [seg][w]
    int b = blockIdx.y;
    int w0 = blockIdx.x * TW2;
    const float* gb = g + (size_t)b * PLANE + w0;
    int t = threadIdx.x;

    // stage raw g (coalesced 64B runs)
    for (int f = t; f < NH * TW2; f += 256) {
        int k = f >> 4, w = f & 15;
        hs[f] = gb[k * NW + w];        // f == k*16+w
    }
    __syncthreads();
    // per-segment minima of raw g
    {
        int s = t >> 4, w = t & 15;
        float m = hs[(s * 32) * TW2 + w];
#pragma unroll
        for (int u = 1; u < 32; ++u) m = fminf(m, hs[(s * 32 + u) * TW2 + w]);
        smin[t] = m;                   // t == s*16+w
    }
    __syncthreads();
    // h = g + k^2 in place
    for (int f = t; f < NH * TW2; f += 256) {
        int k = f >> 4;
        hs[f] += (float)(k * k);
    }
    __syncthreads();

    int w = t & 15, q = t >> 4;
    int i0 = q * 32;
    float best[32], neg2i[32];
#pragma unroll
    for (int j = 0; j < 32; ++j) {
        best[j] = BIG;
        neg2i[j] = (float)(-2 * (i0 + j));
    }
    float bmax = BIG;  // true-space max over outputs of current best
    for (int step = 0; step < 31; ++step) {
        int r = (step + 1) >> 1;
        float gapf = (float)(32 * (r - 1) + 1);
        float gap2 = gapf * gapf;
        if ((step & 1) && gap2 >= bmax) break;     // all further rings pruned
        int s = (step & 1) ? (q - r) : (q + r);    // step0 -> home (r=0)
        if (s < 0 || s >= 16) continue;
        if (step && (gap2 + smin[s * TW2 + w] >= bmax)) continue;
        float s32 = (float)(s * 32);
#pragma unroll 4
        for (int u = 0; u < 32; ++u) {
            float a = hs[(s * 32 + u) * TW2 + w];
            float kf = s32 + (float)u;
#pragma unroll
            for (int j = 0; j < 32; ++j)
                best[j] = fminf(best[j], fmaf(neg2i[j], kf, a));
        }
        // recompute true-space bmax (exact: integers < 2^24 on finite path)
        float ifl0 = (float)i0;
        bmax = fmaf(ifl0, ifl0, best[0]);
#pragma unroll
        for (int j = 1; j < 32; ++j) {
            float ifl = (float)(i0 + j);
            bmax = fmaxf(bmax, fmaf(ifl, ifl, best[j]));
        }
    }
    float* ob = out + (size_t)b * PLANE + w0 + w;
#pragma unroll
    for (int j = 0; j < 32; ++j) {
        float ifl = (float)(i0 + j);
        ob[(size_t)(i0 + j) * NW] = fmaf(ifl, ifl, best[j]);  // exact
    }
}

// ---------------------------------------------------------------------------
// K3: same algorithm along axis 2 (W, contiguous lines) + sqrt + NaN mask.
// Block = 256 threads: 16 lines (b*NH+h), thread (line = t&15, q = t>>4).
// LDS transposed [k][line] with pad 17 to keep both staging writes and
// eval reads conflict-free.
// ---------------------------------------------------------------------------
#define LN 16
#define LDW 17
__global__ __launch_bounds__(256) void k_pass_w(const float* __restrict__ g,
                                                const float* __restrict__ x,
                                                float* __restrict__ out) {
    __shared__ float hs[NW * LDW];     // ~34.8 KB
    __shared__ float smin[16 * LN];
    int line0 = blockIdx.x * LN;
    const float* gb = g + (size_t)line0 * NW;
    int t = threadIdx.x;

    for (int f = t; f < LN * NW; f += 256) {
        int line = f >> 9, k = f & 511;
        hs[k * LDW + line] = gb[f];    // gb[line*512+k] == gb[f]
    }
    __syncthreads();
    {
        int s = t >> 4, line = t & 15;
        float m = hs[(s * 32) * LDW + line];
#pragma unroll
        for (int u = 1; u < 32; ++u) m = fminf(m, hs[(s * 32 + u) * LDW + line]);
        smin[t] = m;                   // t == s*16+line
    }
    __syncthreads();
    for (int f = t; f < LN * NW; f += 256) {
        int k = f & 511;
        hs[k * LDW + (f >> 9)] += (float)(k * k);
    }
    __syncthreads();

    int line = t & 15, q = t >> 4;
    int i0 = q * 32;
    float best[32], neg2i[32];
#pragma unroll
    for (int j = 0; j < 32; ++j) {
        best[j] = BIG;
        neg2i[j] = (float)(-2 * (i0 + j));
    }
    float bmax = BIG;  // true-space
    for (int step = 0; step < 31; ++step) {
        int r = (step + 1) >> 1;
        float gapf = (float)(32 * (r - 1) + 1);
        float gap2 = gapf * gapf;
        if ((step & 1) && gap2 >= bmax) break;
        int s = (step & 1) ? (q - r) : (q + r);
        if (s < 0 || s >= 16) continue;
        if (step && (gap2 + smin[s * LN + line] >= bmax)) continue;
        float s32 = (float)(s * 32);
#pragma unroll 4
        for (int u = 0; u < 32; ++u) {
            float a = hs[(s * 32 + u) * LDW + line];
            float kf = s32 + (float)u;
#pragma unroll
            for (int j = 0; j < 32; ++j)
                best[j] = fminf(best[j], fmaf(neg2i[j], kf, a));
        }
        float ifl0 = (float)i0;
        bmax = fmaf(ifl0, ifl0, best[0]);
#pragma unroll
        for (int j = 1; j < 32; ++j) {
            float ifl = (float)(i0 + j);
            bmax = fmaxf(bmax, fmaf(ifl, ifl, best[j]));
        }
    }
    const size_t base = (size_t)(line0 + line) * NW;
#pragma unroll
    for (int j = 0; j < 32; ++j) {
        int i = i0 + j;
        float ifl = (float)i;
        float m = fmaf(ifl, ifl, best[j]);
        float v = sqrtf(m);
        float xv = x[base + i];
        out[base + i] = isnan(xv) ? __builtin_nanf("") : v;
    }
}

extern "C" void kernel_launch(void* const* d_in, const int* in_sizes, int n_in,
                              void* d_out, int out_size, void* d_ws, size_t ws_size,
                              hipStream_t stream) {
    (void)in_sizes; (void)n_in; (void)out_size; (void)ws_size;
    const float* x = (const float*)d_in[0];
    float* out = (float*)d_out;
    float* ws = (float*)d_ws;  // NB*PLANE*4 = 16.8 MB

    // K1: x -> out (d^2 after B-axis pass)
    k_pass_b<<<dim3(PLANE / 4 / 256), 256, 0, stream>>>(x, out);
    // K2: min-plus along H: out -> ws
    k_pass_h<<<dim3(NW / TW2, NB), 256, 0, stream>>>(out, ws);
    // K3: min-plus along W + sqrt + NaN: ws -> out
    k_pass_w<<<dim3(NB * NH / LN), 256, 0, stream>>>(ws, x, out);
}

// Round 4
// 37.122 us; speedup vs baseline: 7.5647x; 1.7359x over previous
//
#include <hip/hip_runtime.h>
#include <math.h>

#define NB 16
#define NH 512
#define NW 512
#define PLANE (NH * NW)
#define INF_D 1.0e9f
#define BIG 3.0e38f
#define LDW 17
#define NSEG 64  // 512 / 8

// ---------------------------------------------------------------------------
// K1: exact 1-D nearest-zero distance along axis 0 (B), squared. float4.
// Replicates the reference's fwd/bwd min scans bit-exactly.
// ---------------------------------------------------------------------------
__global__ __launch_bounds__(256) void k_pass_b(const float* __restrict__ x,
                                                float* __restrict__ d2) {
    int idx4 = (blockIdx.x * 256 + threadIdx.x) * 4;
    if (idx4 >= PLANE) return;
    float4 d0[NB], d[NB];
#pragma unroll
    for (int b = 0; b < NB; ++b) {
        float4 v = *reinterpret_cast<const float4*>(&x[(size_t)b * PLANE + idx4]);
        d0[b].x = (v.x == 0.0f) ? 0.0f : INF_D;
        d0[b].y = (v.y == 0.0f) ? 0.0f : INF_D;
        d0[b].z = (v.z == 0.0f) ? 0.0f : INF_D;
        d0[b].w = (v.w == 0.0f) ? 0.0f : INF_D;
    }
#pragma unroll
    for (int c = 0; c < 4; ++c) {
        float cc = INF_D;
#pragma unroll
        for (int b = 0; b < NB; ++b) {
            cc = fminf(cc + 1.0f, ((float*)&d0[b])[c]);
            ((float*)&d[b])[c] = cc;
        }
        cc = INF_D;
#pragma unroll
        for (int b = NB - 1; b >= 0; --b) {
            cc = fminf(cc + 1.0f, ((float*)&d0[b])[c]);
            ((float*)&d[b])[c] = fminf(((float*)&d[b])[c], cc);
        }
    }
#pragma unroll
    for (int b = 0; b < NB; ++b) {
        float4 o;
        o.x = d[b].x * d[b].x;
        o.y = d[b].y * d[b].y;
        o.z = d[b].z * d[b].z;
        o.w = d[b].w * d[b].w;
        *reinterpret_cast<float4*>(&d2[(size_t)b * PLANE + idx4]) = o;
    }
}

// ---------------------------------------------------------------------------
// K2: exact min-plus parabola along axis 1 (H), seg=8 ring pruning.
// Block = 1024 threads: one b, 16-wide w tile, all 512 i.
// Thread (w = t&15, q = t>>4, q in 0..63) owns outputs i = 8q..8q+7.
// h[k] = g[k]+k^2 in LDS; candidate = fma(-2i,k,h[k]); out = i^2 + min.
// All finite-path values are integers < 2^24 -> bit-exact vs reference.
// True-space prune: bmax = max_j (i_j^2 + best[j]); segment s at ring r
// skippable when gap^2 + min_seg(g) >= bmax, gap = 8(r-1)+1; all rings >= r
// skippable when gap^2 >= bmax.
// ---------------------------------------------------------------------------
__global__ __launch_bounds__(1024) void k_pass_h(const float* __restrict__ g,
                                                 float* __restrict__ out) {
    __shared__ float hs[NH * LDW];
    __shared__ float smin[NSEG * 16];
    int b = blockIdx.y;
    int w0 = blockIdx.x * 16;
    const float* gb = g + (size_t)b * PLANE + w0;
    int t = threadIdx.x;

    for (int f = t; f < NH * 16; f += 1024) {
        int k = f >> 4, w = f & 15;
        hs[k * LDW + w] = gb[k * NW + w];
    }
    __syncthreads();
    {
        int s = t >> 4, w = t & 15;
        float m = hs[(s * 8) * LDW + w];
#pragma unroll
        for (int u = 1; u < 8; ++u) m = fminf(m, hs[(s * 8 + u) * LDW + w]);
        smin[t] = m;  // t == s*16+w
    }
    __syncthreads();
    for (int f = t; f < NH * 16; f += 1024) {
        int k = f >> 4;
        hs[k * LDW + (f & 15)] += (float)(k * k);
    }
    __syncthreads();

    int w = t & 15, q = t >> 4;
    int i0 = q * 8;
    float best[8], neg2i[8];
#pragma unroll
    for (int j = 0; j < 8; ++j) {
        best[j] = BIG;
        neg2i[j] = (float)(-2 * (i0 + j));
    }
    float bmax = BIG;  // true-space
    for (int step = 0; step < 2 * NSEG - 1; ++step) {
        int r = (step + 1) >> 1;
        float gapf = (float)(8 * (r - 1) + 1);
        float gap2 = gapf * gapf;
        if ((step & 1) && gap2 >= bmax) break;
        int s = (step & 1) ? (q - r) : (q + r);
        if (s < 0 || s >= NSEG) continue;
        if (step && (gap2 + smin[s * 16 + w] >= bmax)) continue;
        float s8 = (float)(s * 8);
#pragma unroll
        for (int u = 0; u < 8; ++u) {
            float a = hs[(s * 8 + u) * LDW + w];
            float kf = s8 + (float)u;
#pragma unroll
            for (int j = 0; j < 8; ++j)
                best[j] = fminf(best[j], fmaf(neg2i[j], kf, a));
        }
        float i0f = (float)i0;
        bmax = fmaf(i0f, i0f, best[0]);
#pragma unroll
        for (int j = 1; j < 8; ++j) {
            float ifl = (float)(i0 + j);
            bmax = fmaxf(bmax, fmaf(ifl, ifl, best[j]));
        }
    }
    float* ob = out + (size_t)b * PLANE + w0 + w;
#pragma unroll
    for (int j = 0; j < 8; ++j) {
        float ifl = (float)(i0 + j);
        ob[(size_t)(i0 + j) * NW] = fmaf(ifl, ifl, best[j]);  // exact
    }
}

// ---------------------------------------------------------------------------
// K3: same along axis 2 (W, contiguous lines) + sqrt + NaN mask.
// Block = 1024 threads: 16 lines, thread (line = t&15, q = t>>4).
// Outputs are 8 consecutive i in one line -> float4 epilogue.
// ---------------------------------------------------------------------------
__global__ __launch_bounds__(1024) void k_pass_w(const float* __restrict__ g,
                                                 const float* __restrict__ x,
                                                 float* __restrict__ out) {
    __shared__ float hs[NW * LDW];
    __shared__ float smin[NSEG * 16];
    int line0 = blockIdx.x * 16;
    const float* gb = g + (size_t)line0 * NW;
    int t = threadIdx.x;

    for (int f = t; f < 16 * NW; f += 1024) {
        int line = f >> 9, k = f & 511;
        hs[k * LDW + line] = gb[f];  // gb[line*512+k] == gb[f]
    }
    __syncthreads();
    {
        int s = t >> 4, line = t & 15;
        float m = hs[(s * 8) * LDW + line];
#pragma unroll
        for (int u = 1; u < 8; ++u) m = fminf(m, hs[(s * 8 + u) * LDW + line]);
        smin[t] = m;  // t == s*16+line
    }
    __syncthreads();
    for (int f = t; f < 16 * NW; f += 1024) {
        int k = f & 511;
        hs[k * LDW + (f >> 9)] += (float)(k * k);
    }
    __syncthreads();

    int line = t & 15, q = t >> 4;
    int i0 = q * 8;
    float best[8], neg2i[8];
#pragma unroll
    for (int j = 0; j < 8; ++j) {
        best[j] = BIG;
        neg2i[j] = (float)(-2 * (i0 + j));
    }
    float bmax = BIG;
    for (int step = 0; step < 2 * NSEG - 1; ++step) {
        int r = (step + 1) >> 1;
        float gapf = (float)(8 * (r - 1) + 1);
        float gap2 = gapf * gapf;
        if ((step & 1) && gap2 >= bmax) break;
        int s = (step & 1) ? (q - r) : (q + r);
        if (s < 0 || s >= NSEG) continue;
        if (step && (gap2 + smin[s * 16 + line] >= bmax)) continue;
        float s8 = (float)(s * 8);
#pragma unroll
        for (int u = 0; u < 8; ++u) {
            float a = hs[(s * 8 + u) * LDW + line];
            float kf = s8 + (float)u;
#pragma unroll
            for (int j = 0; j < 8; ++j)
                best[j] = fminf(best[j], fmaf(neg2i[j], kf, a));
        }
        float i0f = (float)i0;
        bmax = fmaf(i0f, i0f, best[0]);
#pragma unroll
        for (int j = 1; j < 8; ++j) {
            float ifl = (float)(i0 + j);
            bmax = fmaxf(bmax, fmaf(ifl, ifl, best[j]));
        }
    }
    const size_t base = (size_t)(line0 + line) * NW + i0;
    float4 xa = *reinterpret_cast<const float4*>(&x[base]);
    float4 xb = *reinterpret_cast<const float4*>(&x[base + 4]);
    float v[8];
#pragma unroll
    for (int j = 0; j < 8; ++j) {
        float ifl = (float)(i0 + j);
        v[j] = sqrtf(fmaf(ifl, ifl, best[j]));
    }
    float4 oa, ob4;
    oa.x = isnan(xa.x) ? __builtin_nanf("") : v[0];
    oa.y = isnan(xa.y) ? __builtin_nanf("") : v[1];
    oa.z = isnan(xa.z) ? __builtin_nanf("") : v[2];
    oa.w = isnan(xa.w) ? __builtin_nanf("") : v[3];
    ob4.x = isnan(xb.x) ? __builtin_nanf("") : v[4];
    ob4.y = isnan(xb.y) ? __builtin_nanf("") : v[5];
    ob4.z = isnan(xb.z) ? __builtin_nanf("") : v[6];
    ob4.w = isnan(xb.w) ? __builtin_nanf("") : v[7];
    *reinterpret_cast<float4*>(&out[base]) = oa;
    *reinterpret_cast<float4*>(&out[base + 4]) = ob4;
}

extern "C" void kernel_launch(void* const* d_in, const int* in_sizes, int n_in,
                              void* d_out, int out_size, void* d_ws, size_t ws_size,
                              hipStream_t stream) {
    (void)in_sizes; (void)n_in; (void)out_size; (void)ws_size;
    const float* x = (const float*)d_in[0];
    float* out = (float*)d_out;
    float* ws = (float*)d_ws;  // NB*PLANE*4 = 16.8 MB

    // K1: x -> out (d^2 after B-axis pass)
    k_pass_b<<<dim3(PLANE / 4 / 256), 256, 0, stream>>>(x, out);
    // K2: min-plus along H: out -> ws
    k_pass_h<<<dim3(NW / 16, NB), 1024, 0, stream>>>(out, ws);
    // K3: min-plus along W + sqrt + NaN: ws -> out
    k_pass_w<<<dim3(NB * NH / 16), 1024, 0, stream>>>(ws, x, out);
}